// Round 1
// 271.555 us; speedup vs baseline: 1.0550x; 1.0550x over previous
//
#include <hip/hip_runtime.h>
#include <hip/hip_bf16.h>
#include <stdint.h>

#define E_ 8
#define H_ 2048
#define I_ 1408
#define T_ 2048
#define K_ 2
#define G_ 128

typedef __bf16 bf16;
typedef bf16 bf16x8 __attribute__((ext_vector_type(8)));
typedef float f32x4 __attribute__((ext_vector_type(4)));

__device__ __forceinline__ uint32_t prm(uint32_t hi, uint32_t lo, uint32_t sel) {
    return __builtin_amdgcn_perm(hi, lo, sel);
}

// Scale-folded dequant tables: bf16(e2m1[m]*s) split into high/low byte LUTs.
struct DequantTab { uint32_t thi0, thi1, tlo0, tlo1; };

__device__ __forceinline__ DequantTab build_tab(float s) {
    union { bf16 h[8]; uint32_t u[4]; } tb;
    tb.h[0] = (bf16)(0.0f);
    tb.h[1] = (bf16)(0.5f * s);
    tb.h[2] = (bf16)(1.0f * s);
    tb.h[3] = (bf16)(1.5f * s);
    tb.h[4] = (bf16)(2.0f * s);
    tb.h[5] = (bf16)(3.0f * s);
    tb.h[6] = (bf16)(4.0f * s);
    tb.h[7] = (bf16)(6.0f * s);
    DequantTab t;
    t.thi0 = prm(tb.u[1], tb.u[0], 0x07050301u);
    t.tlo0 = prm(tb.u[1], tb.u[0], 0x06040200u);
    t.thi1 = prm(tb.u[3], tb.u[2], 0x07050301u);
    t.tlo1 = prm(tb.u[3], tb.u[2], 0x06040200u);
    return t;
}

// 8 fp4 (one u32, k-order) -> 8 scaled bf16 as uint4. ~21 VALU ops.
__device__ __forceinline__ uint4 dequant8t(uint32_t p, const DequantTab& t) {
    const uint32_t pr = p >> 4;
    const uint32_t pe = p  & 0x07070707u;
    const uint32_t po = pr & 0x07070707u;
    const uint32_t He = prm(t.thi1, t.thi0, pe) | ((p  & 0x08080808u) << 4);
    const uint32_t Le = prm(t.tlo1, t.tlo0, pe);
    const uint32_t Ho = prm(t.thi1, t.thi0, po) | ((pr & 0x08080808u) << 4);
    const uint32_t Lo = prm(t.tlo1, t.tlo0, po);
    const uint32_t E01 = prm(He, Le, 0x05010400u);
    const uint32_t E23 = prm(He, Le, 0x07030602u);
    const uint32_t O01 = prm(Ho, Lo, 0x05010400u);
    const uint32_t O23 = prm(Ho, Lo, 0x07030602u);
    return make_uint4(prm(O01, E01, 0x05040100u),
                      prm(O01, E01, 0x07060302u),
                      prm(O23, E23, 0x05040100u),
                      prm(O23, E23, 0x07060302u));
}

// async 16B global -> LDS DMA (wave-uniform-base + lane-linear dest)
__device__ __forceinline__ void gld16(void* lds, const void* g) {
    __builtin_amdgcn_global_load_lds(
        (__attribute__((address_space(1))) void*)g,
        (__attribute__((address_space(3))) void*)lds, 16, 0, 0);
}

// ---------------- routing ----------------
__global__ void route_count(const int* __restrict__ topk_idx, int* __restrict__ counts) {
    int p = blockIdx.x * blockDim.x + threadIdx.x;
    if (p < T_ * K_) atomicAdd(&counts[topk_idx[p]], 1);
}

// tiles of 128 token-pairs (max total tiles = 4096/128 + 8 = 40)
__global__ void route_scan(const int* __restrict__ counts, int* __restrict__ offsets,
                           int* __restrict__ tmap) {
    if (threadIdx.x == 0) {
        int acc = 0, ti = 0;
        for (int e = 0; e < E_; e++) {
            offsets[e] = acc;
            int nt = (counts[e] + 127) >> 7;
            for (int j = 0; j < nt; j++) tmap[ti++] = (e << 16) | j;
            acc += counts[e];
        }
        offsets[E_] = acc;
        for (; ti < 64; ti++) tmap[ti] = -1;
    }
}

__global__ void route_fill(const int* __restrict__ topk_idx, const float* __restrict__ topk_w,
                           int* __restrict__ cursors, const int* __restrict__ offsets,
                           int* __restrict__ tok, float* __restrict__ wgt,
                           int* __restrict__ inv) {
    int p = blockIdx.x * blockDim.x + threadIdx.x;
    if (p < T_ * K_) {
        int e = topk_idx[p];
        int slot = atomicAdd(&cursors[e], 1);
        int idx = offsets[e] + slot;
        tok[idx] = p / K_;
        wgt[idx] = topk_w[p];
        inv[p] = idx;
    }
}

// x f32 -> bf16
__global__ __launch_bounds__(256)
void xcast_kernel(const float* __restrict__ x, uint4* __restrict__ xb) {
    const int i = blockIdx.x * 256 + threadIdx.x;
    const float4 a = ((const float4*)x)[i * 2];
    const float4 b = ((const float4*)x)[i * 2 + 1];
    union { uint4 u; bf16 h[8]; } r;
    r.h[0] = (bf16)a.x; r.h[1] = (bf16)a.y; r.h[2] = (bf16)a.z; r.h[3] = (bf16)a.w;
    r.h[4] = (bf16)b.x; r.h[5] = (bf16)b.y; r.h[6] = (bf16)b.z; r.h[7] = (bf16)b.w;
    xb[i] = r.u;
}

// ---------------- GEMM1: 128tok x 64i tile, BK=64 ----------------
// Pipelined: x double-buffered via gld16 DMA; packed weights prefetched into
// regs one step ahead; raw s_barrier + counted vmcnt (never 0 in steady state).
// LDS chunk swizzle: 16B chunk c of row r stored at chunk c^(r&7).
__global__ __launch_bounds__(256, 3)
void gemm1t_kernel(const bf16* __restrict__ xb,
                   const uint32_t* __restrict__ gate_packed,
                   const float* __restrict__ gate_scales,
                   const uint32_t* __restrict__ up_packed,
                   const float* __restrict__ up_scales,
                   const int* __restrict__ offsets,
                   const int* __restrict__ tmap,
                   const int* __restrict__ tok, bf16* __restrict__ h_buf)
{
    const int tm = tmap[blockIdx.x];
    if (tm < 0) return;
    const int e = tm >> 16, ty = tm & 0xffff;       // 128-token tile
    const int row0 = offsets[e];
    const int cnt = offsets[e + 1] - row0;
    const int itile = blockIdx.y;                    // 64 i-cols

    __shared__ __align__(16) bf16 xs[2][128][64];    // 32 KB double-buffered
    __shared__ __align__(16) bf16 wgs[64][64];       // 8 KB
    __shared__ __align__(16) bf16 wus[64][64];       // 8 KB

    const int tid = threadIdx.x;

    // --- x staging roles: 4 gld16/thread/step, swizzled source chunk ---
    const int xr = tid >> 3;             // 0..31
    const int xc = tid & 7;              // dest chunk
    const int xch = (xc ^ (xr & 7)) * 8; // row&7 invariant across j (+32 rows)
    const bf16* xsrc[4];
    bf16* xdst[4];
#pragma unroll
    for (int j = 0; j < 4; ++j) {
        int g = ty * 128 + xr + j * 32;
        g = (g < cnt) ? g : (cnt - 1);
        xsrc[j] = xb + (size_t)tok[row0 + g] * H_ + xch;
        xdst[j] = &xs[0][xr + j * 32][xc * 8];   // lane-linear within wave
    }

    // --- weight staging roles: 1 uint4 (4 u32 = 32 fp4) per thread/step ---
    const int mat  = tid >> 7;           // 0 = gate, 1 = up
    const int id   = tid & 127;
    const int wrow = id >> 1;            // 0..63
    const int quad = id & 1;             // u32 group {0..3} or {4..7}
    const int irow = itile * 64 + wrow;
    const uint32_t* wp_row = (mat ? up_packed : gate_packed)
        + (size_t)e * I_ * (H_ / 8) + (size_t)irow * (H_ / 8) + quad * 4;
    const float* ws_row = (mat ? up_scales : gate_scales)
        + (size_t)e * (H_ / G_) * I_ + irow;
    bf16 (* const wdst)[64] = mat ? wus : wgs;

    const int wave = tid >> 6, lane = tid & 63;
    const int wy = wave >> 1, wx = wave & 1;
    const int lrow = lane & 15, kq = lane >> 4;

    f32x4 accg[4][2] = {};
    f32x4 accu[4][2] = {};

    // prologue: t=0 staging in flight
    float sc_cur = ws_row[0];
    uint4 pw = *(const uint4*)(wp_row);
#pragma unroll
    for (int j = 0; j < 4; ++j) gld16(xdst[j], xsrc[j]);

    constexpr int NG = H_ / G_;          // 16 groups
    constexpr int NT = 2 * NG;           // 32 K-steps
    for (int kg = 0; kg < NG; ++kg) {
        const int kgn = (kg + 1 < NG) ? kg + 1 : kg;
        const float sc_nxt = ws_row[(size_t)kgn * I_];   // group-scale prefetch
        const DequantTab tw = build_tab(sc_cur);
#pragma unroll
        for (int kh2 = 0; kh2 < 2; ++kh2) {
            const int t  = kg * 2 + kh2;
            const int tn = (t < NT - 1) ? t + 1 : t;
            // issue t+1 staging: weights -> regs, x -> other LDS buffer
            const uint4 pwn = *(const uint4*)(wp_row + tn * 8);
#pragma unroll
            for (int j = 0; j < 4; ++j)
                gld16(xdst[j] + (kh2 ^ 1) * (128 * 64), xsrc[j] + tn * 64);
            __builtin_amdgcn_sched_barrier(0);
            // dequant step t into single-buffered weight tiles
            {
                uint4 d0 = dequant8t(pw.x, tw);
                uint4 d1 = dequant8t(pw.y, tw);
                uint4 d2 = dequant8t(pw.z, tw);
                uint4 d3 = dequant8t(pw.w, tw);
                const int cb = quad * 4, rs = wrow & 7;
                *(uint4*)&wdst[wrow][((cb + 0) ^ rs) * 8] = d0;
                *(uint4*)&wdst[wrow][((cb + 1) ^ rs) * 8] = d1;
                *(uint4*)&wdst[wrow][((cb + 2) ^ rs) * 8] = d2;
                *(uint4*)&wdst[wrow][((cb + 3) ^ rs) * 8] = d3;
            }
            __builtin_amdgcn_sched_barrier(0);
            // drain x_t DMA + LDS writes; keep the t+1 group (and kh2==0: the
            // scale prefetch) in flight.
            if (kh2 == 0) asm volatile("s_waitcnt vmcnt(6) lgkmcnt(0)" ::: "memory");
            else          asm volatile("s_waitcnt vmcnt(5) lgkmcnt(0)" ::: "memory");
            __builtin_amdgcn_s_barrier();
            __builtin_amdgcn_sched_barrier(0);
            // compute step t
#pragma unroll
            for (int kh = 0; kh < 2; ++kh) {             // two K=32 slices
                bf16x8 a[4], bg[2], bu[2];
#pragma unroll
                for (int mi = 0; mi < 4; ++mi) {
                    const int ra = wy * 64 + mi * 16 + lrow;
                    a[mi] = *(const bf16x8*)&xs[kh2][ra][((kh * 4 + kq) ^ (ra & 7)) * 8];
                }
#pragma unroll
                for (int ni = 0; ni < 2; ++ni) {
                    const int rb = wx * 32 + ni * 16 + lrow;
                    const int cb2 = ((kh * 4 + kq) ^ (rb & 7)) * 8;
                    bg[ni] = *(const bf16x8*)&wgs[rb][cb2];
                    bu[ni] = *(const bf16x8*)&wus[rb][cb2];
                }
#pragma unroll
                for (int mi = 0; mi < 4; ++mi)
#pragma unroll
                    for (int ni = 0; ni < 2; ++ni) {
                        accg[mi][ni] = __builtin_amdgcn_mfma_f32_16x16x32_bf16(a[mi], bg[ni], accg[mi][ni], 0, 0, 0);
                        accu[mi][ni] = __builtin_amdgcn_mfma_f32_16x16x32_bf16(a[mi], bu[ni], accu[mi][ni], 0, 0, 0);
                    }
            }
            __builtin_amdgcn_sched_barrier(0);
            asm volatile("s_waitcnt lgkmcnt(0)" ::: "memory");
            __builtin_amdgcn_s_barrier();
            pw = pwn;
        }
        sc_cur = sc_nxt;
    }

    // epilogue: h = silu(g)*u. C layout: col=lane&15, row=(lane>>4)*4+r
#pragma unroll
    for (int mi = 0; mi < 4; ++mi)
#pragma unroll
        for (int ni = 0; ni < 2; ++ni) {
            const int icol = itile * 64 + wx * 32 + ni * 16 + lrow;
#pragma unroll
            for (int r = 0; r < 4; ++r) {
                const int grow = ty * 128 + wy * 64 + mi * 16 + kq * 4 + r;
                if (grow < cnt) {
                    const float gv = accg[mi][ni][r];
                    const float hv = gv / (1.f + __expf(-gv)) * accu[mi][ni][r];
                    h_buf[(size_t)(row0 + grow) * I_ + icol] = (bf16)hv;
                }
            }
        }
}

// ---------------- GEMM2: 128tok x 128h tile, BK=64, same pipeline ----------------
__global__ __launch_bounds__(256, 3)
void gemm2t_kernel(const bf16* __restrict__ h_buf,
                   const uint32_t* __restrict__ down_packed,
                   const float* __restrict__ down_scales,
                   const int* __restrict__ offsets,
                   const int* __restrict__ tmap,
                   const float* __restrict__ wgt, float* __restrict__ yp)
{
    const int tm = tmap[blockIdx.x];
    if (tm < 0) return;
    const int e = tm >> 16, ty = tm & 0xffff;
    const int row0 = offsets[e];
    const int cnt = offsets[e + 1] - row0;
    const int htile = blockIdx.y;                    // 128 h-cols

    __shared__ __align__(16) bf16 hs[2][128][64];    // 32 KB double-buffered
    __shared__ __align__(16) bf16 wds[128][64];      // 16 KB

    const int tid = threadIdx.x;

    // --- h staging: 4 gld16/thread/step ---
    const int xr = tid >> 3;
    const int xc = tid & 7;
    const int xch = (xc ^ (xr & 7)) * 8;
    const bf16* hsrc[4];
    bf16* hdst[4];
#pragma unroll
    for (int j = 0; j < 4; ++j) {
        int g = ty * 128 + xr + j * 32;
        g = (g < cnt) ? g : (cnt - 1);
        hsrc[j] = h_buf + (size_t)(row0 + g) * I_ + xch;
        hdst[j] = &hs[0][xr + j * 32][xc * 8];
    }

    // --- weight staging: 128 rows x 8 u32 -> 1 uint4 per thread/step ---
    const int wrow = tid >> 1;           // 0..127
    const int quad = tid & 1;
    const int hrow = htile * 128 + wrow;
    const uint32_t* dp_row = down_packed + (size_t)e * H_ * (I_ / 8) + (size_t)hrow * (I_ / 8) + quad * 4;
    const float* ds_row = down_scales + (size_t)e * (I_ / G_) * H_ + hrow;

    const int wave = tid >> 6, lane = tid & 63;
    const int wy = wave >> 1, wx = wave & 1;
    const int lrow = lane & 15, kq = lane >> 4;

    f32x4 acc[4][4] = {};

    float sc_cur = ds_row[0];
    uint4 pw = *(const uint4*)(dp_row);
#pragma unroll
    for (int j = 0; j < 4; ++j) gld16(hdst[j], hsrc[j]);

    constexpr int NG = I_ / G_;          // 11 groups
    constexpr int NT = 2 * NG;           // 22 K-steps
    for (int kg = 0; kg < NG; ++kg) {
        const int kgn = (kg + 1 < NG) ? kg + 1 : kg;
        const float sc_nxt = ds_row[(size_t)kgn * H_];
        const DequantTab td = build_tab(sc_cur);
#pragma unroll
        for (int kh2 = 0; kh2 < 2; ++kh2) {
            const int t  = kg * 2 + kh2;
            const int tn = (t < NT - 1) ? t + 1 : t;
            const uint4 pwn = *(const uint4*)(dp_row + tn * 8);
#pragma unroll
            for (int j = 0; j < 4; ++j)
                gld16(hdst[j] + (kh2 ^ 1) * (128 * 64), hsrc[j] + tn * 64);
            __builtin_amdgcn_sched_barrier(0);
            {
                uint4 d0 = dequant8t(pw.x, td);
                uint4 d1 = dequant8t(pw.y, td);
                uint4 d2 = dequant8t(pw.z, td);
                uint4 d3 = dequant8t(pw.w, td);
                const int cb = quad * 4, rs = wrow & 7;
                *(uint4*)&wds[wrow][((cb + 0) ^ rs) * 8] = d0;
                *(uint4*)&wds[wrow][((cb + 1) ^ rs) * 8] = d1;
                *(uint4*)&wds[wrow][((cb + 2) ^ rs) * 8] = d2;
                *(uint4*)&wds[wrow][((cb + 3) ^ rs) * 8] = d3;
            }
            __builtin_amdgcn_sched_barrier(0);
            if (kh2 == 0) asm volatile("s_waitcnt vmcnt(6) lgkmcnt(0)" ::: "memory");
            else          asm volatile("s_waitcnt vmcnt(5) lgkmcnt(0)" ::: "memory");
            __builtin_amdgcn_s_barrier();
            __builtin_amdgcn_sched_barrier(0);
#pragma unroll
            for (int kh = 0; kh < 2; ++kh) {
                bf16x8 a[4], b[4];
#pragma unroll
                for (int mi = 0; mi < 4; ++mi) {
                    const int ra = wy * 64 + mi * 16 + lrow;
                    a[mi] = *(const bf16x8*)&hs[kh2][ra][((kh * 4 + kq) ^ (ra & 7)) * 8];
                }
#pragma unroll
                for (int ni = 0; ni < 4; ++ni) {
                    const int rb = wx * 64 + ni * 16 + lrow;
                    b[ni] = *(const bf16x8*)&wds[rb][((kh * 4 + kq) ^ (rb & 7)) * 8];
                }
#pragma unroll
                for (int mi = 0; mi < 4; ++mi)
#pragma unroll
                    for (int ni = 0; ni < 4; ++ni)
                        acc[mi][ni] = __builtin_amdgcn_mfma_f32_16x16x32_bf16(a[mi], b[ni], acc[mi][ni], 0, 0, 0);
            }
            __builtin_amdgcn_sched_barrier(0);
            asm volatile("s_waitcnt lgkmcnt(0)" ::: "memory");
            __builtin_amdgcn_s_barrier();
            pw = pwn;
        }
        sc_cur = sc_nxt;
    }

    // epilogue: plain stores of wgt-scaled partials
#pragma unroll
    for (int mi = 0; mi < 4; ++mi)
#pragma unroll
        for (int r = 0; r < 4; ++r) {
            const int grow = ty * 128 + wy * 64 + mi * 16 + kq * 4 + r;
            if (grow < cnt) {
                const float w = wgt[row0 + grow];
#pragma unroll
                for (int ni = 0; ni < 4; ++ni) {
                    const int col = htile * 128 + wx * 64 + ni * 16 + lrow;
                    yp[(size_t)(row0 + grow) * H_ + col] = acc[mi][ni][r] * w;
                }
            }
        }
}

// ---------------- combine: out[t] = sum over K pairs ----------------
__global__ __launch_bounds__(256)
void combine_kernel(const float* __restrict__ yp, const int* __restrict__ inv,
                    float* __restrict__ out) {
    const int idx = blockIdx.x * 256 + threadIdx.x;   // T_*H_/4 units
    const int t = idx >> 9;                            // / (H_/4 = 512)
    const int c = idx & 511;
    const float4 a = ((const float4*)yp)[(size_t)inv[t * 2] * (H_ / 4) + c];
    const float4 b = ((const float4*)yp)[(size_t)inv[t * 2 + 1] * (H_ / 4) + c];
    float4 o;
    o.x = a.x + b.x; o.y = a.y + b.y; o.z = a.z + b.z; o.w = a.w + b.w;
    ((float4*)out)[idx] = o;
}

extern "C" void kernel_launch(void* const* d_in, const int* in_sizes, int n_in,
                              void* d_out, int out_size, void* d_ws, size_t ws_size,
                              hipStream_t stream) {
    const float* x = (const float*)d_in[0];
    const uint32_t* gate_packed = (const uint32_t*)d_in[1];
    const float* gate_scales = (const float*)d_in[2];
    const uint32_t* up_packed = (const uint32_t*)d_in[3];
    const float* up_scales = (const float*)d_in[4];
    const uint32_t* down_packed = (const uint32_t*)d_in[5];
    const float* down_scales = (const float*)d_in[6];
    const int* topk_idx = (const int*)d_in[7];
    const float* topk_w = (const float*)d_in[8];
    float* out = (float*)d_out;

    // workspace layout (bytes)
    char* ws = (char*)d_ws;
    int* counts  = (int*)ws;              // 32
    int* cursors = (int*)(ws + 32);       // 32
    int* offsets = (int*)(ws + 64);       // 64
    int* tmap    = (int*)(ws + 128);      // 512 (128 ints)
    int* tok     = (int*)(ws + 640);      // 16384
    float* wgt   = (float*)(ws + 17024);  // 16384
    int* inv     = (int*)(ws + 33408);    // 16384
    bf16* h_buf  = (bf16*)(ws + 49792);   // 11,534,336
    bf16* xb     = (bf16*)(ws + 49792 + 11534336ull);                 // 8,388,608
    float* yp    = (float*)(ws + 49792 + 11534336ull + 8388608ull);   // 33,554,432

    hipMemsetAsync(d_ws, 0, 1024, stream);

    route_count<<<(T_ * K_ + 255) / 256, 256, 0, stream>>>(topk_idx, counts);
    route_scan<<<1, 64, 0, stream>>>(counts, offsets, tmap);
    route_fill<<<(T_ * K_ + 255) / 256, 256, 0, stream>>>(topk_idx, topk_w, cursors, offsets,
                                                          tok, wgt, inv);
    xcast_kernel<<<T_ * H_ / 8 / 256, 256, 0, stream>>>(x, (uint4*)xb);

    dim3 g1(40, I_ / 64);    // x = 128-token tile (weight reuse), y = itile
    gemm1t_kernel<<<g1, 256, 0, stream>>>(xb, gate_packed, gate_scales, up_packed, up_scales,
                                          offsets, tmap, tok, h_buf);
    dim3 g2(40, H_ / 128);   // x = 128-token tile, y = htile
    gemm2t_kernel<<<g2, 256, 0, stream>>>(h_buf, down_packed, down_scales,
                                          offsets, tmap, wgt, yp);
    combine_kernel<<<T_ * H_ / 4 / 256, 256, 0, stream>>>(yp, inv, out);
}